// Round 16
// baseline (650.001 us; speedup 1.0000x reference)
//
#include <hip/hip_runtime.h>
#include <hip/hip_cooperative_groups.h>

namespace cg = cooperative_groups;

#define NN 50000
#define NE 500000
#define HID 64
#define TROW 1040   // ushorts/node: [jp<32][o<16][2] f16 pairs + b2 row f16 @1024
#define MAXG 2048

typedef unsigned int  uint;
typedef unsigned short ushort;
typedef __fp16 h2 __attribute__((ext_vector_type(2)));

__device__ __forceinline__ ushort f2h(float f) {
    union { __fp16 h; ushort s; } v; v.h = (__fp16)f; return v.s;
}
__device__ __forceinline__ h2 u2h2(uint u) {
    union { uint u; h2 h; } v; v.u = u; return v.h;
}
__device__ __forceinline__ float h2lo(uint u) {
    union { ushort s; __fp16 h; } v; v.s = (ushort)(u & 0xffffu); return (float)v.h;
}
__device__ __forceinline__ float h2hi(uint u) {
    union { ushort s; __fp16 h; } v; v.s = (ushort)(u >> 16); return (float)v.h;
}

// 256-thread block exclusive scan of deg[beg,end) -> offs, starting at carry0.
__device__ void blk_scan_range(const int* __restrict__ deg, int* __restrict__ offs,
                               int beg, int end, int carry0)
{
    __shared__ int wsum[4];
    __shared__ int wtot;
    const int tid = threadIdx.x;
    int carry = carry0;
    for (int base = beg; base < end; base += 256) {
        const int idx = base + tid;
        const bool inb = idx < end;
        int v = inb ? deg[idx] : 0;
        int s = v;
        #pragma unroll
        for (int d = 1; d < 64; d <<= 1) {
            int t = __shfl_up(s, d, 64);
            if ((tid & 63) >= d) s += t;
        }
        if ((tid & 63) == 63) wsum[tid >> 6] = s;
        __syncthreads();
        if (tid == 0) {
            int c = 0;
            #pragma unroll
            for (int w = 0; w < 4; ++w) { int t = wsum[w]; wsum[w] = c; c += t; }
            wtot = c;
        }
        __syncthreads();
        if (inb) offs[idx] = carry + wsum[tid >> 6] + (s - v);
        carry += wtot;
        __syncthreads();
    }
}

struct MegaParams {
    const float *x, *ef;
    const int *src, *dst;
    const float *W1, *b1, *W2, *b2, *bias;
    float *out;
    ushort *T;
    float *msgbuf, *W2R, *W1T;
    int *deg_s, *deg_d, *offs_s, *offs_d, *pos_s, *pos_d, *eidx_s, *bsum_s, *bsum_d;
};

// ===========================================================================
// Cooperative mega-kernel: r14/15 proven phase bodies, 6 dispatches -> 1.
// Round-15 accounting: ~45us of the 211 were inter-dispatch gaps; grid.sync()
// barriers replace them. Edge phase = edge_msg6 verbatim (its 70us was shown
// invariant to ILP/occupancy/pipelining tweaks across r13-r15).
// ===========================================================================
__global__ __launch_bounds__(256, 4) void dgc_mega(MegaParams p)
{
    cg::grid_group gg = cg::this_grid();
    const int tid = threadIdx.x;
    const int bid = blockIdx.x;
    const int G = gridDim.x;
    const int gtid = bid * 256 + tid;
    const int gstride = G * 256;

    // ---- P0: zero degree histograms (replaces hipMemsetAsync) ----
    for (int i = gtid; i < NN; i += gstride) { p.deg_s[i] = 0; p.deg_d[i] = 0; }
    gg.sync();

    // ---- P1: count ranks+degrees; W2R/W1T transforms ----
    for (int e = gtid; e < NE; e += gstride) {
        p.pos_s[e] = atomicAdd(p.deg_s + p.src[e], 1);
        p.pos_d[e] = atomicAdd(p.deg_d + p.dst[e], 1);
    }
    for (int t = gtid; t < 65 * 256; t += gstride) {
        const int j = t >> 8, col = t & 255;        // col = i*16 + o
        const int i = col >> 4, o = col & 15;
        const float v = (j < 64) ? p.W2[j * 256 + col] : p.b2[col];
        p.W2R[j * 256 + o * 16 + i] = v;            // [j][o][i]
    }
    for (int t = gtid; t < 64 * 16; t += gstride) {
        const int j = t >> 4, i = t & 15;
        p.W1T[t] = p.W1[i * HID + j];               // W1T[j][i] = W1[i][j]
    }
    gg.sync();

    // ---- P2: grid-wide exclusive scans of deg_s/deg_d ----
    const int tile = (NN + G - 1) / G;
    const int nbeg = bid * tile;
    const int nend = (nbeg + tile < NN) ? (nbeg + tile) : NN;
    {   // P2a: per-block tile sums
        int ls = 0, ld = 0;
        for (int i = nbeg + tid; i < nend; i += 256) { ls += p.deg_s[i]; ld += p.deg_d[i]; }
        #pragma unroll
        for (int d = 32; d > 0; d >>= 1) {
            ls += __shfl_down(ls, d, 64);
            ld += __shfl_down(ld, d, 64);
        }
        __shared__ int reds[4], redd[4];
        if ((tid & 63) == 0) { reds[tid >> 6] = ls; redd[tid >> 6] = ld; }
        __syncthreads();
        if (tid == 0) {
            p.bsum_s[bid] = reds[0] + reds[1] + reds[2] + reds[3];
            p.bsum_d[bid] = redd[0] + redd[1] + redd[2] + redd[3];
        }
        __syncthreads();
    }
    gg.sync();
    // P2b: scan the block sums (in place, exclusive)
    if (bid == 0)      blk_scan_range(p.bsum_s, p.bsum_s, 0, G, 0);
    else if (bid == 1) blk_scan_range(p.bsum_d, p.bsum_d, 0, G, 0);
    gg.sync();
    // P2c: per-block tile scans seeded by block prefix
    blk_scan_range(p.deg_s, p.offs_s, nbeg, nend, p.bsum_s[bid]);
    blk_scan_range(p.deg_d, p.offs_d, nbeg, nend, p.bsum_d[bid]);
    if (gtid == 0) { p.offs_s[NN] = NE; p.offs_d[NN] = NE; }
    gg.sync();

    // ---- P3: scatter src-CSR + tprep (f16 j-pair T) ----
    for (int e = gtid; e < NE; e += gstride)
        p.eidx_s[p.offs_s[p.src[e]] + p.pos_s[e]] = e;
    {
        const int jt = tid >> 4, o = tid & 15;
        const int off0 = (jt >> 1) * 32 + o * 2 + (jt & 1);

        float w0[16], w1[16], w2[16], w3[16];
        {
            const float4* p0 = reinterpret_cast<const float4*>(p.W2R + (jt     ) * 256 + o * 16);
            const float4* p1 = reinterpret_cast<const float4*>(p.W2R + (jt + 16) * 256 + o * 16);
            const float4* p2 = reinterpret_cast<const float4*>(p.W2R + (jt + 32) * 256 + o * 16);
            const float4* p3 = reinterpret_cast<const float4*>(p.W2R + (jt + 48) * 256 + o * 16);
            #pragma unroll
            for (int q = 0; q < 4; ++q) {
                float4 a = p0[q]; w0[4*q]=a.x; w0[4*q+1]=a.y; w0[4*q+2]=a.z; w0[4*q+3]=a.w;
                float4 b = p1[q]; w1[4*q]=b.x; w1[4*q+1]=b.y; w1[4*q+2]=b.z; w1[4*q+3]=b.w;
                float4 c = p2[q]; w2[4*q]=c.x; w2[4*q+1]=c.y; w2[4*q+2]=c.z; w2[4*q+3]=c.w;
                float4 d = p3[q]; w3[4*q]=d.x; w3[4*q+1]=d.y; w3[4*q+2]=d.z; w3[4*q+3]=d.w;
            }
        }
        float wb[16];
        if (jt == 0) {
            const float4* pb = reinterpret_cast<const float4*>(p.W2R + 64 * 256 + o * 16);
            #pragma unroll
            for (int q = 0; q < 4; ++q) {
                float4 a = pb[q]; wb[4*q]=a.x; wb[4*q+1]=a.y; wb[4*q+2]=a.z; wb[4*q+3]=a.w;
            }
        }

        for (int n = bid; n < NN; n += G) {
            float xr[16];
            {
                const float4* q = reinterpret_cast<const float4*>(p.x) + (size_t)n * 4;
                float4 a = q[0], b = q[1], c = q[2], d = q[3];
                xr[0]=a.x; xr[1]=a.y; xr[2]=a.z;  xr[3]=a.w;
                xr[4]=b.x; xr[5]=b.y; xr[6]=b.z;  xr[7]=b.w;
                xr[8]=c.x; xr[9]=c.y; xr[10]=c.z; xr[11]=c.w;
                xr[12]=d.x; xr[13]=d.y; xr[14]=d.z; xr[15]=d.w;
            }
            ushort* tw = p.T + (size_t)n * TROW;

            float s0 = xr[0]*w0[0], s1 = xr[0]*w1[0], s2 = xr[0]*w2[0], s3 = xr[0]*w3[0];
            #pragma unroll
            for (int i = 1; i < 16; ++i) {
                s0 = fmaf(xr[i], w0[i], s0);
                s1 = fmaf(xr[i], w1[i], s1);
                s2 = fmaf(xr[i], w2[i], s2);
                s3 = fmaf(xr[i], w3[i], s3);
            }
            tw[off0]       = f2h(s0);
            tw[off0 + 256] = f2h(s1);
            tw[off0 + 512] = f2h(s2);
            tw[off0 + 768] = f2h(s3);
            if (jt == 0) {
                float sb = xr[0]*wb[0];
                #pragma unroll
                for (int i = 1; i < 16; ++i) sb = fmaf(xr[i], wb[i], sb);
                tw[1024 + o] = f2h(sb);
            }
        }
    }
    gg.sync();

    // ---- P4: edge messages (edge_msg6 body) ----
    for (int k = gtid; k < NE; k += gstride) {
        const int e = p.eidx_s[k];
        const int s = p.src[e];

        float ea[16];
        {
            const float4* q = reinterpret_cast<const float4*>(p.ef) + (size_t)e * 4;
            float4 a = q[0], b = q[1], c = q[2], d = q[3];
            ea[0]=a.x; ea[1]=a.y; ea[2]=a.z;  ea[3]=a.w;
            ea[4]=b.x; ea[5]=b.y; ea[6]=b.z;  ea[7]=b.w;
            ea[8]=c.x; ea[9]=c.y; ea[10]=c.z; ea[11]=c.w;
            ea[12]=d.x; ea[13]=d.y; ea[14]=d.z; ea[15]=d.w;
        }

        const ushort* tr = p.T + (size_t)s * TROW;

        float m0[16];
        {
            uint4 a = *reinterpret_cast<const uint4*>(tr + 1024);
            uint4 b = *reinterpret_cast<const uint4*>(tr + 1032);
            m0[0]=h2lo(a.x);  m0[1]=h2hi(a.x);  m0[2]=h2lo(a.y);  m0[3]=h2hi(a.y);
            m0[4]=h2lo(a.z);  m0[5]=h2hi(a.z);  m0[6]=h2lo(a.w);  m0[7]=h2hi(a.w);
            m0[8]=h2lo(b.x);  m0[9]=h2hi(b.x);  m0[10]=h2lo(b.y); m0[11]=h2hi(b.y);
            m0[12]=h2lo(b.z); m0[13]=h2hi(b.z); m0[14]=h2lo(b.w); m0[15]=h2hi(b.w);
        }

        for (int jp = 0; jp < 32; ++jp) {
            const float* __restrict__ wr = p.W1T + jp * 32;
            float h0a = p.b1[2 * jp], h0b = p.b1[2 * jp + 1];
            #pragma unroll
            for (int i = 0; i < 16; ++i) {
                h0a = fmaf(ea[i], wr[i], h0a);
                h0b = fmaf(ea[i], wr[16 + i], h0b);
            }
            h0a = fmaxf(h0a, 0.f); h0b = fmaxf(h0b, 0.f);
            const h2 hp0 = __builtin_amdgcn_cvt_pkrtz(h0a, h0b);

            const uint4 a0 = *reinterpret_cast<const uint4*>(tr + jp * 32);
            const uint4 b0 = *reinterpret_cast<const uint4*>(tr + jp * 32 + 8);
            const uint4 c0 = *reinterpret_cast<const uint4*>(tr + jp * 32 + 16);
            const uint4 d0 = *reinterpret_cast<const uint4*>(tr + jp * 32 + 24);

            m0[0]  = __builtin_amdgcn_fdot2(hp0, u2h2(a0.x), m0[0],  false);
            m0[1]  = __builtin_amdgcn_fdot2(hp0, u2h2(a0.y), m0[1],  false);
            m0[2]  = __builtin_amdgcn_fdot2(hp0, u2h2(a0.z), m0[2],  false);
            m0[3]  = __builtin_amdgcn_fdot2(hp0, u2h2(a0.w), m0[3],  false);
            m0[4]  = __builtin_amdgcn_fdot2(hp0, u2h2(b0.x), m0[4],  false);
            m0[5]  = __builtin_amdgcn_fdot2(hp0, u2h2(b0.y), m0[5],  false);
            m0[6]  = __builtin_amdgcn_fdot2(hp0, u2h2(b0.z), m0[6],  false);
            m0[7]  = __builtin_amdgcn_fdot2(hp0, u2h2(b0.w), m0[7],  false);
            m0[8]  = __builtin_amdgcn_fdot2(hp0, u2h2(c0.x), m0[8],  false);
            m0[9]  = __builtin_amdgcn_fdot2(hp0, u2h2(c0.y), m0[9],  false);
            m0[10] = __builtin_amdgcn_fdot2(hp0, u2h2(c0.z), m0[10], false);
            m0[11] = __builtin_amdgcn_fdot2(hp0, u2h2(c0.w), m0[11], false);
            m0[12] = __builtin_amdgcn_fdot2(hp0, u2h2(d0.x), m0[12], false);
            m0[13] = __builtin_amdgcn_fdot2(hp0, u2h2(d0.y), m0[13], false);
            m0[14] = __builtin_amdgcn_fdot2(hp0, u2h2(d0.z), m0[14], false);
            m0[15] = __builtin_amdgcn_fdot2(hp0, u2h2(d0.w), m0[15], false);
        }

        const int d = p.dst[e];
        const int slot = p.offs_d[d] + p.pos_d[e];
        float4* mr = reinterpret_cast<float4*>(p.msgbuf + (size_t)slot * 16);
        mr[0] = make_float4(m0[0], m0[1], m0[2], m0[3]);
        mr[1] = make_float4(m0[4], m0[5], m0[6], m0[7]);
        mr[2] = make_float4(m0[8], m0[9], m0[10], m0[11]);
        mr[3] = make_float4(m0[12], m0[13], m0[14], m0[15]);
    }
    gg.sync();

    // ---- P5: gather mean (+bias, zero-deg fallback) ----
    for (int t = gtid; t < NN * 4; t += gstride) {
        const int n = t >> 2;
        const int oq = t & 3;
        const int beg = p.offs_d[n], end = p.offs_d[n + 1];
        float4 s = make_float4(0.f, 0.f, 0.f, 0.f);
        for (int k = beg; k < end; ++k) {
            const float4 v = *reinterpret_cast<const float4*>(p.msgbuf + (size_t)k * 16 + oq * 4);
            s.x += v.x; s.y += v.y; s.z += v.z; s.w += v.w;
        }
        const int d = end - beg;
        float4 r;
        if (d > 0) {
            const float inv = 1.f / (float)d;
            r = make_float4(s.x * inv, s.y * inv, s.z * inv, s.w * inv);
        } else {
            r = *reinterpret_cast<const float4*>(p.x + (size_t)n * 16 + oq * 4);
        }
        const float4 bv = *reinterpret_cast<const float4*>(p.bias + oq * 4);
        r.x += bv.x; r.y += bv.y; r.z += bv.z; r.w += bv.w;
        *reinterpret_cast<float4*>(p.out + (size_t)n * 16 + oq * 4) = r;
    }
}

// ===========================================================================
// FALLBACK A: r14 proven 5-kernel pipeline (if cooperative launch fails)
// ===========================================================================
__global__ __launch_bounds__(256) void count_w2r(
    const int* __restrict__ src, const int* __restrict__ dst,
    int* __restrict__ deg_s, int* __restrict__ pos_s,
    int* __restrict__ deg_d, int* __restrict__ pos_d,
    const float* __restrict__ W2, const float* __restrict__ b2,
    const float* __restrict__ W1, float* __restrict__ W2R,
    float* __restrict__ W1T)
{
    const int nbc = (NE + 255) / 256;
    if ((int)blockIdx.x < nbc) {
        const int e = blockIdx.x * 256 + threadIdx.x;
        if (e < NE) {
            pos_s[e] = atomicAdd(deg_s + src[e], 1);
            pos_d[e] = atomicAdd(deg_d + dst[e], 1);
        }
    } else {
        const int t = (blockIdx.x - nbc) * 256 + threadIdx.x;
        if (t < 64 * 16) {
            const int j = t >> 4, i = t & 15;
            W1T[t] = W1[i * HID + j];
        }
        if (t < 65 * 256) {
            const int j = t >> 8;
            const int col = t & 255;
            const int i = col >> 4, o = col & 15;
            const float v = (j < 64) ? W2[j * 256 + col] : b2[col];
            W2R[j * 256 + o * 16 + i] = v;
        }
    }
}

__global__ __launch_bounds__(1024) void dgc_scan2(
    const int* __restrict__ degA, int* __restrict__ offA,
    const int* __restrict__ degB, int* __restrict__ offB)
{
    const int* __restrict__ deg = blockIdx.x ? degB : degA;
    int* __restrict__ offs      = blockIdx.x ? offB : offA;
    __shared__ int wsum[16];
    const int tid = threadIdx.x;
    const int lane = tid & 63;
    const int wid = tid >> 6;
    int carry = 0;
    for (int base = 0; base < NN; base += 1024) {
        const int idx = base + tid;
        const int v = (idx < NN) ? deg[idx] : 0;
        int s = v;
        #pragma unroll
        for (int d = 1; d < 64; d <<= 1) {
            int t = __shfl_up(s, d, 64);
            if (lane >= d) s += t;
        }
        if (lane == 63) wsum[wid] = s;
        __syncthreads();
        if (wid == 0 && lane < 16) {
            int w = wsum[lane];
            #pragma unroll
            for (int d = 1; d < 16; d <<= 1) {
                int t = __shfl_up(w, d, 64);
                if (lane >= d) w += t;
            }
            wsum[lane] = w;
        }
        __syncthreads();
        const int wpre = (wid == 0) ? 0 : wsum[wid - 1];
        if (idx < NN) offs[idx] = carry + wpre + (s - v);
        carry += wsum[15];
        __syncthreads();
    }
    if (tid == 0) offs[NN] = carry;
}

__global__ __launch_bounds__(256) void scatter_tprep(
    const int* __restrict__ src, const int* __restrict__ pos_s,
    const int* __restrict__ offs_s, int* __restrict__ eidx_s,
    const float* __restrict__ x, const float* __restrict__ W2R,
    ushort* __restrict__ T)
{
    const int nbs = (NE + 255) / 256;
    if ((int)blockIdx.x < nbs) {
        const int e = blockIdx.x * 256 + threadIdx.x;
        if (e < NE) eidx_s[offs_s[src[e]] + pos_s[e]] = e;
        return;
    }
    const int bid = blockIdx.x - nbs;
    const int tid = threadIdx.x;
    const int jt = tid >> 4, o = tid & 15;
    const int off0 = (jt >> 1) * 32 + o * 2 + (jt & 1);

    float w0[16], w1[16], w2[16], w3[16];
    {
        const float4* p0 = reinterpret_cast<const float4*>(W2R + (jt     ) * 256 + o * 16);
        const float4* p1 = reinterpret_cast<const float4*>(W2R + (jt + 16) * 256 + o * 16);
        const float4* p2 = reinterpret_cast<const float4*>(W2R + (jt + 32) * 256 + o * 16);
        const float4* p3 = reinterpret_cast<const float4*>(W2R + (jt + 48) * 256 + o * 16);
        #pragma unroll
        for (int q = 0; q < 4; ++q) {
            float4 a = p0[q]; w0[4*q]=a.x; w0[4*q+1]=a.y; w0[4*q+2]=a.z; w0[4*q+3]=a.w;
            float4 b = p1[q]; w1[4*q]=b.x; w1[4*q+1]=b.y; w1[4*q+2]=b.z; w1[4*q+3]=b.w;
            float4 c = p2[q]; w2[4*q]=c.x; w2[4*q+1]=c.y; w2[4*q+2]=c.z; w2[4*q+3]=c.w;
            float4 d = p3[q]; w3[4*q]=d.x; w3[4*q+1]=d.y; w3[4*q+2]=d.z; w3[4*q+3]=d.w;
        }
    }
    float wb[16];
    if (jt == 0) {
        const float4* pb = reinterpret_cast<const float4*>(W2R + 64 * 256 + o * 16);
        #pragma unroll
        for (int q = 0; q < 4; ++q) {
            float4 a = pb[q]; wb[4*q]=a.x; wb[4*q+1]=a.y; wb[4*q+2]=a.z; wb[4*q+3]=a.w;
        }
    }

    for (int n = bid; n < NN; n += 2048) {
        float xr[16];
        {
            const float4* q = reinterpret_cast<const float4*>(x) + (size_t)n * 4;
            float4 a = q[0], b = q[1], c = q[2], d = q[3];
            xr[0]=a.x; xr[1]=a.y; xr[2]=a.z;  xr[3]=a.w;
            xr[4]=b.x; xr[5]=b.y; xr[6]=b.z;  xr[7]=b.w;
            xr[8]=c.x; xr[9]=c.y; xr[10]=c.z; xr[11]=c.w;
            xr[12]=d.x; xr[13]=d.y; xr[14]=d.z; xr[15]=d.w;
        }
        ushort* tw = T + (size_t)n * TROW;

        float s0 = xr[0]*w0[0], s1 = xr[0]*w1[0], s2 = xr[0]*w2[0], s3 = xr[0]*w3[0];
        #pragma unroll
        for (int i = 1; i < 16; ++i) {
            s0 = fmaf(xr[i], w0[i], s0);
            s1 = fmaf(xr[i], w1[i], s1);
            s2 = fmaf(xr[i], w2[i], s2);
            s3 = fmaf(xr[i], w3[i], s3);
        }
        tw[off0]       = f2h(s0);
        tw[off0 + 256] = f2h(s1);
        tw[off0 + 512] = f2h(s2);
        tw[off0 + 768] = f2h(s3);
        if (jt == 0) {
            float sb = xr[0]*wb[0];
            #pragma unroll
            for (int i = 1; i < 16; ++i) sb = fmaf(xr[i], wb[i], sb);
            tw[1024 + o] = f2h(sb);
        }
    }
}

__global__ __launch_bounds__(256) void edge_msg6(
    const int* __restrict__ eidx_s, const int* __restrict__ src,
    const int* __restrict__ dst, const float* __restrict__ ef,
    const float* __restrict__ W1T, const float* __restrict__ b1,
    const ushort* __restrict__ T, const int* __restrict__ offs_d,
    const int* __restrict__ pos_d, float* __restrict__ msgbuf)
{
    const int k = blockIdx.x * blockDim.x + threadIdx.x;
    if (k >= NE) return;
    const int e = eidx_s[k];
    const int s = src[e];

    float ea[16];
    {
        const float4* q = reinterpret_cast<const float4*>(ef) + (size_t)e * 4;
        float4 a = q[0], b = q[1], c = q[2], d = q[3];
        ea[0]=a.x; ea[1]=a.y; ea[2]=a.z;  ea[3]=a.w;
        ea[4]=b.x; ea[5]=b.y; ea[6]=b.z;  ea[7]=b.w;
        ea[8]=c.x; ea[9]=c.y; ea[10]=c.z; ea[11]=c.w;
        ea[12]=d.x; ea[13]=d.y; ea[14]=d.z; ea[15]=d.w;
    }

    const ushort* tr = T + (size_t)s * TROW;

    float m0[16];
    {
        uint4 a = *reinterpret_cast<const uint4*>(tr + 1024);
        uint4 b = *reinterpret_cast<const uint4*>(tr + 1032);
        m0[0]=h2lo(a.x);  m0[1]=h2hi(a.x);  m0[2]=h2lo(a.y);  m0[3]=h2hi(a.y);
        m0[4]=h2lo(a.z);  m0[5]=h2hi(a.z);  m0[6]=h2lo(a.w);  m0[7]=h2hi(a.w);
        m0[8]=h2lo(b.x);  m0[9]=h2hi(b.x);  m0[10]=h2lo(b.y); m0[11]=h2hi(b.y);
        m0[12]=h2lo(b.z); m0[13]=h2hi(b.z); m0[14]=h2lo(b.w); m0[15]=h2hi(b.w);
    }

    for (int jp = 0; jp < 32; ++jp) {
        const float* __restrict__ wr = W1T + jp * 32;
        float h0a = b1[2 * jp], h0b = b1[2 * jp + 1];
        #pragma unroll
        for (int i = 0; i < 16; ++i) {
            h0a = fmaf(ea[i], wr[i], h0a);
            h0b = fmaf(ea[i], wr[16 + i], h0b);
        }
        h0a = fmaxf(h0a, 0.f); h0b = fmaxf(h0b, 0.f);
        const h2 hp0 = __builtin_amdgcn_cvt_pkrtz(h0a, h0b);

        const uint4 a0 = *reinterpret_cast<const uint4*>(tr + jp * 32);
        const uint4 b0 = *reinterpret_cast<const uint4*>(tr + jp * 32 + 8);
        const uint4 c0 = *reinterpret_cast<const uint4*>(tr + jp * 32 + 16);
        const uint4 d0 = *reinterpret_cast<const uint4*>(tr + jp * 32 + 24);

        m0[0]  = __builtin_amdgcn_fdot2(hp0, u2h2(a0.x), m0[0],  false);
        m0[1]  = __builtin_amdgcn_fdot2(hp0, u2h2(a0.y), m0[1],  false);
        m0[2]  = __builtin_amdgcn_fdot2(hp0, u2h2(a0.z), m0[2],  false);
        m0[3]  = __builtin_amdgcn_fdot2(hp0, u2h2(a0.w), m0[3],  false);
        m0[4]  = __builtin_amdgcn_fdot2(hp0, u2h2(b0.x), m0[4],  false);
        m0[5]  = __builtin_amdgcn_fdot2(hp0, u2h2(b0.y), m0[5],  false);
        m0[6]  = __builtin_amdgcn_fdot2(hp0, u2h2(b0.z), m0[6],  false);
        m0[7]  = __builtin_amdgcn_fdot2(hp0, u2h2(b0.w), m0[7],  false);
        m0[8]  = __builtin_amdgcn_fdot2(hp0, u2h2(c0.x), m0[8],  false);
        m0[9]  = __builtin_amdgcn_fdot2(hp0, u2h2(c0.y), m0[9],  false);
        m0[10] = __builtin_amdgcn_fdot2(hp0, u2h2(c0.z), m0[10], false);
        m0[11] = __builtin_amdgcn_fdot2(hp0, u2h2(c0.w), m0[11], false);
        m0[12] = __builtin_amdgcn_fdot2(hp0, u2h2(d0.x), m0[12], false);
        m0[13] = __builtin_amdgcn_fdot2(hp0, u2h2(d0.y), m0[13], false);
        m0[14] = __builtin_amdgcn_fdot2(hp0, u2h2(d0.z), m0[14], false);
        m0[15] = __builtin_amdgcn_fdot2(hp0, u2h2(d0.w), m0[15], false);
    }

    const int d = dst[e];
    const int slot = offs_d[d] + pos_d[e];
    float4* mr = reinterpret_cast<float4*>(msgbuf + (size_t)slot * 16);
    mr[0] = make_float4(m0[0], m0[1], m0[2], m0[3]);
    mr[1] = make_float4(m0[4], m0[5], m0[6], m0[7]);
    mr[2] = make_float4(m0[8], m0[9], m0[10], m0[11]);
    mr[3] = make_float4(m0[12], m0[13], m0[14], m0[15]);
}

__global__ __launch_bounds__(256) void gather_mean3(
    const float* __restrict__ msgbuf, const int* __restrict__ offs_d,
    const float* __restrict__ x, const float* __restrict__ bias,
    float* __restrict__ out)
{
    const int t = blockIdx.x * blockDim.x + threadIdx.x;
    if (t >= NN * 4) return;
    const int n = t >> 2;
    const int oq = t & 3;
    const int beg = offs_d[n], end = offs_d[n + 1];
    float4 s = make_float4(0.f, 0.f, 0.f, 0.f);
    for (int k = beg; k < end; ++k) {
        const float4 v = *reinterpret_cast<const float4*>(msgbuf + (size_t)k * 16 + oq * 4);
        s.x += v.x; s.y += v.y; s.z += v.z; s.w += v.w;
    }
    const int d = end - beg;
    float4 r;
    if (d > 0) {
        const float inv = 1.f / (float)d;
        r = make_float4(s.x * inv, s.y * inv, s.z * inv, s.w * inv);
    } else {
        r = *reinterpret_cast<const float4*>(x + (size_t)n * 16 + oq * 4);
    }
    const float4 bv = *reinterpret_cast<const float4*>(bias + oq * 4);
    r.x += bv.x; r.y += bv.y; r.z += bv.z; r.w += bv.w;
    *reinterpret_cast<float4*>(out + (size_t)n * 16 + oq * 4) = r;
}

// ===========================================================================
// FALLBACK B: r2 proven path (~36.4 MB ws)
// ===========================================================================
__global__ __launch_bounds__(1024) void dgc_scan(
    const int* __restrict__ deg, int* __restrict__ offs, int n)
{
    __shared__ int wsum[16];
    const int tid = threadIdx.x;
    const int lane = tid & 63;
    const int wid = tid >> 6;
    int carry = 0;
    for (int base = 0; base < n; base += 1024) {
        const int idx = base + tid;
        const int v = (idx < n) ? deg[idx] : 0;
        int s = v;
        #pragma unroll
        for (int d = 1; d < 64; d <<= 1) {
            int t = __shfl_up(s, d, 64);
            if (lane >= d) s += t;
        }
        if (lane == 63) wsum[wid] = s;
        __syncthreads();
        if (wid == 0 && lane < 16) {
            int w = wsum[lane];
            #pragma unroll
            for (int d = 1; d < 16; d <<= 1) {
                int t = __shfl_up(w, d, 64);
                if (lane >= d) w += t;
            }
            wsum[lane] = w;
        }
        __syncthreads();
        const int wpre = (wid == 0) ? 0 : wsum[wid - 1];
        if (idx < n) offs[idx] = carry + wpre + (s - v);
        carry += wsum[15];
        __syncthreads();
    }
    if (tid == 0) offs[n] = carry;
}

__global__ __launch_bounds__(256) void dgc_edge_csr(
    const float* __restrict__ x, const float* __restrict__ ef,
    const int* __restrict__ src, const int* __restrict__ dst,
    const float* __restrict__ W1, const float* __restrict__ b1,
    const float* __restrict__ W2, const float* __restrict__ b2,
    float* __restrict__ msg, int* __restrict__ pos, int* __restrict__ deg)
{
    const int e = blockIdx.x * blockDim.x + threadIdx.x;
    if (e >= NE) return;
    float efv[16];
    {
        const float4* p = reinterpret_cast<const float4*>(ef) + (size_t)e * 4;
        float4 a = p[0], b = p[1], c = p[2], d = p[3];
        efv[0]=a.x; efv[1]=a.y; efv[2]=a.z;  efv[3]=a.w;
        efv[4]=b.x; efv[5]=b.y; efv[6]=b.z;  efv[7]=b.w;
        efv[8]=c.x; efv[9]=c.y; efv[10]=c.z; efv[11]=c.w;
        efv[12]=d.x; efv[13]=d.y; efv[14]=d.z; efv[15]=d.w;
    }
    const int s = src[e];
    float xs[16];
    {
        const float4* p = reinterpret_cast<const float4*>(x) + (size_t)s * 4;
        float4 a = p[0], b = p[1], c = p[2], d = p[3];
        xs[0]=a.x; xs[1]=a.y; xs[2]=a.z;  xs[3]=a.w;
        xs[4]=b.x; xs[5]=b.y; xs[6]=b.z;  xs[7]=b.w;
        xs[8]=c.x; xs[9]=c.y; xs[10]=c.z; xs[11]=c.w;
        xs[12]=d.x; xs[13]=d.y; xs[14]=d.z; xs[15]=d.w;
    }
    float m[16];
    #pragma unroll
    for (int o = 0; o < 16; ++o) m[o] = 0.f;
    #pragma unroll
    for (int i = 0; i < 16; ++i) {
        const float xi = xs[i];
        #pragma unroll
        for (int o = 0; o < 16; ++o) m[o] = fmaf(xi, b2[i * 16 + o], m[o]);
    }
    for (int j = 0; j < HID; ++j) {
        float hj = b1[j];
        #pragma unroll
        for (int i = 0; i < 16; ++i) hj = fmaf(efv[i], W1[i * HID + j], hj);
        hj = fmaxf(hj, 0.f);
        const float* __restrict__ w2r = W2 + (size_t)j * 256;
        float t[16];
        #pragma unroll
        for (int o = 0; o < 16; ++o) t[o] = 0.f;
        #pragma unroll
        for (int i = 0; i < 16; ++i) {
            const float xi = xs[i];
            #pragma unroll
            for (int o = 0; o < 16; ++o) t[o] = fmaf(xi, w2r[i * 16 + o], t[o]);
        }
        #pragma unroll
        for (int o = 0; o < 16; ++o) m[o] = fmaf(hj, t[o], m[o]);
    }
    float4* mr = reinterpret_cast<float4*>(msg + (size_t)e * 16);
    mr[0] = make_float4(m[0], m[1], m[2], m[3]);
    mr[1] = make_float4(m[4], m[5], m[6], m[7]);
    mr[2] = make_float4(m[8], m[9], m[10], m[11]);
    mr[3] = make_float4(m[12], m[13], m[14], m[15]);
    pos[e] = atomicAdd(deg + dst[e], 1);
}

__global__ __launch_bounds__(256) void dgc_scatter(
    const int* __restrict__ dst, const int* __restrict__ pos,
    const int* __restrict__ offs, int* __restrict__ eidx)
{
    const int e = blockIdx.x * blockDim.x + threadIdx.x;
    if (e >= NE) return;
    eidx[offs[dst[e]] + pos[e]] = e;
}

__global__ __launch_bounds__(256) void dgc_gather(
    const float* __restrict__ msg, const int* __restrict__ offs,
    const int* __restrict__ eidx, const float* __restrict__ x,
    const float* __restrict__ bias, float* __restrict__ out)
{
    const int t = blockIdx.x * blockDim.x + threadIdx.x;
    if (t >= NN * 16) return;
    const int n = t >> 4;
    const int o = t & 15;
    const int beg = offs[n], end = offs[n + 1];
    float s = 0.f;
    for (int k = beg; k < end; ++k)
        s += msg[(size_t)eidx[k] * 16 + o];
    const int d = end - beg;
    const float v = (d > 0) ? (s / (float)d) : x[t];
    out[t] = v + bias[o];
}

extern "C" void kernel_launch(void* const* d_in, const int* in_sizes, int n_in,
                              void* d_out, int out_size, void* d_ws, size_t ws_size,
                              hipStream_t stream) {
    const float* x    = (const float*)d_in[0];
    const float* ef   = (const float*)d_in[1];
    const int*   src  = (const int*)d_in[2];
    const int*   dst  = (const int*)d_in[3];
    const float* W1   = (const float*)d_in[4];
    const float* b1   = (const float*)d_in[5];
    const float* W2   = (const float*)d_in[6];
    const float* b2   = (const float*)d_in[7];
    const float* bias = (const float*)d_in[8];
    float* out = (float*)d_out;

    // main-path ws layout
    ushort* T      = (ushort*)d_ws;                       // NN*TROW f16 (104 MB)
    float*  msgbuf = (float*)(T + (size_t)NN * TROW);     // NE*16 f32   (32 MB)
    float*  W2R    = msgbuf + (size_t)NE * 16;            // 65*256
    float*  W1T    = W2R + 65 * 256;                      // 64*16
    int*    deg_s  = (int*)(W1T + 64 * 16);               // NN
    int*    deg_d  = deg_s + NN;                          // NN
    int*    offs_s = deg_d + NN;                          // NN+1
    int*    offs_d = offs_s + NN + 1;                     // NN+1
    int*    pos_s  = offs_d + NN + 1;                     // NE
    int*    pos_d  = pos_s + NE;                          // NE
    int*    eidx_s = pos_d + NE;                          // NE
    int*    bsum_s = eidx_s + NE;                         // MAXG
    int*    bsum_d = bsum_s + MAXG;                       // MAXG
    const size_t needed =
        (size_t)NN * TROW * 2 +
        ((size_t)NE * 16 + 65 * 256 + 64 * 16) * 4 +
        ((size_t)2 * NN + 2 * (NN + 1) + (size_t)3 * NE + 2 * MAXG) * 4;

    const int nbc = (NE + 255) / 256;   // 1954

    if (ws_size >= needed) {
        bool done = false;
        int nbcu = 0;
        if (hipOccupancyMaxActiveBlocksPerMultiprocessor(&nbcu, dgc_mega, 256, 0) == hipSuccess
            && nbcu > 0) {
            int G = nbcu * 256;          // 256 CUs on MI355X
            if (G > MAXG) G = MAXG;
            MegaParams prm;
            prm.x = x; prm.ef = ef; prm.src = src; prm.dst = dst;
            prm.W1 = W1; prm.b1 = b1; prm.W2 = W2; prm.b2 = b2; prm.bias = bias;
            prm.out = out;
            prm.T = T; prm.msgbuf = msgbuf; prm.W2R = W2R; prm.W1T = W1T;
            prm.deg_s = deg_s; prm.deg_d = deg_d; prm.offs_s = offs_s; prm.offs_d = offs_d;
            prm.pos_s = pos_s; prm.pos_d = pos_d; prm.eidx_s = eidx_s;
            prm.bsum_s = bsum_s; prm.bsum_d = bsum_d;
            void* args[] = { &prm };
            if (hipLaunchCooperativeKernel((const void*)dgc_mega, dim3(G), dim3(256),
                                           args, 0, stream) == hipSuccess)
                done = true;
        }
        if (!done) {
            // r14 proven pipeline
            hipMemsetAsync(deg_s, 0, (size_t)2 * NN * sizeof(int), stream);
            count_w2r<<<nbc + 65, 256, 0, stream>>>(
                src, dst, deg_s, pos_s, deg_d, pos_d, W2, b2, W1, W2R, W1T);
            dgc_scan2<<<2, 1024, 0, stream>>>(deg_s, offs_s, deg_d, offs_d);
            scatter_tprep<<<nbc + 2048, 256, 0, stream>>>(
                src, pos_s, offs_s, eidx_s, x, W2R, T);
            edge_msg6<<<nbc, 256, 0, stream>>>(
                eidx_s, src, dst, ef, W1T, b1, T, offs_d, pos_d, msgbuf);
            gather_mean3<<<(NN * 4 + 255) / 256, 256, 0, stream>>>(
                msgbuf, offs_d, x, bias, out);
        }
    } else {
        // r2 fallback
        float* msg  = (float*)d_ws;
        int*   deg  = (int*)(msg + (size_t)NE * 16);
        int*   offs = deg + NN;
        int*   pos  = offs + NN + 1;
        int*   eidx = pos + NE;
        hipMemsetAsync(deg, 0, (size_t)NN * sizeof(int), stream);
        dgc_edge_csr<<<(NE + 255) / 256, 256, 0, stream>>>(
            x, ef, src, dst, W1, b1, W2, b2, msg, pos, deg);
        dgc_scan<<<1, 1024, 0, stream>>>(deg, offs, NN);
        dgc_scatter<<<(NE + 255) / 256, 256, 0, stream>>>(dst, pos, offs, eidx);
        dgc_gather<<<(NN * 16 + 255) / 256, 256, 0, stream>>>(
            msg, offs, eidx, x, bias, out);
    }
}

// Round 17
// 212.306 us; speedup vs baseline: 3.0616x; 3.0616x over previous
//
#include <hip/hip_runtime.h>

#define NN 50000
#define NE 500000
#define FIN 16
#define FOUT 16
#define HID 64
#define TROW 1040   // ushorts/node: [jp<32][o<16][2] f16 pairs (j=2jp,2jp+1) + b2 row f16 @1024

typedef unsigned int  uint;
typedef unsigned short ushort;
typedef __fp16 h2 __attribute__((ext_vector_type(2)));   // matches cvt_pkrtz/fdot2 builtin type

__device__ __forceinline__ ushort f2h(float f) {            // f32 -> f16 bits
    union { __fp16 h; ushort s; } v; v.h = (__fp16)f; return v.s;
}
__device__ __forceinline__ h2 u2h2(uint u) {                // uint -> 2xf16
    union { uint u; h2 h; } v; v.u = u; return v.h;
}
__device__ __forceinline__ float h2lo(uint u) {
    union { ushort s; __fp16 h; } v; v.s = (ushort)(u & 0xffffu); return (float)v.h;
}
__device__ __forceinline__ float h2hi(uint u) {
    union { ushort s; __fp16 h; } v; v.s = (ushort)(u >> 16); return (float)v.h;
}

// ===========================================================================
// MAIN PATH = round-14 proven configuration (210.9us), restored verbatim.
// r16 lesson: cooperative grid.sync() costs ~130-150us/barrier on MI355X
// (device-scope spin across 8 non-coherent XCD L2s) -> mega-kernel 5x WORSE
// than the ~8us/launch gaps it replaced. Separate dispatches win.
// Component floors (measured across r7-r15 probes): edge 70us (FETCH=143MB =
// algorithmic minimum at scattered-64B BW ~2TB/s; invariant to ILP/occ/SWP),
// tprep 35 (104MB write-bound), count 28 (1M atomics x2), gather 17, scan 8.
// ===========================================================================

// blocks [0,1954): count ranks+degrees. blocks [1954,+65): W2R/W1T transforms.
__global__ __launch_bounds__(256) void count_w2r(
    const int* __restrict__ src, const int* __restrict__ dst,
    int* __restrict__ deg_s, int* __restrict__ pos_s,
    int* __restrict__ deg_d, int* __restrict__ pos_d,
    const float* __restrict__ W2, const float* __restrict__ b2,
    const float* __restrict__ W1, float* __restrict__ W2R,
    float* __restrict__ W1T)
{
    const int nbc = (NE + 255) / 256;
    if ((int)blockIdx.x < nbc) {
        const int e = blockIdx.x * 256 + threadIdx.x;
        if (e < NE) {
            pos_s[e] = atomicAdd(deg_s + src[e], 1);
            pos_d[e] = atomicAdd(deg_d + dst[e], 1);
        }
    } else {
        const int t = (blockIdx.x - nbc) * 256 + threadIdx.x;
        if (t < 64 * 16) {
            const int j = t >> 4, i = t & 15;
            W1T[t] = W1[i * HID + j];          // W1T[j][i] = W1[i][j]
        }
        if (t < 65 * 256) {
            const int j = t >> 8;
            const int col = t & 255;           // col = i*16 + o
            const int i = col >> 4, o = col & 15;
            const float v = (j < 64) ? W2[j * 256 + col] : b2[col];
            W2R[j * 256 + o * 16 + i] = v;     // W2R[j][o][i]
        }
    }
}

// two independent exclusive scans (block 0: A, block 1: B), n=NN each
__global__ __launch_bounds__(1024) void dgc_scan2(
    const int* __restrict__ degA, int* __restrict__ offA,
    const int* __restrict__ degB, int* __restrict__ offB)
{
    const int* __restrict__ deg = blockIdx.x ? degB : degA;
    int* __restrict__ offs      = blockIdx.x ? offB : offA;
    __shared__ int wsum[16];
    const int tid = threadIdx.x;
    const int lane = tid & 63;
    const int wid = tid >> 6;
    int carry = 0;
    for (int base = 0; base < NN; base += 1024) {
        const int idx = base + tid;
        const int v = (idx < NN) ? deg[idx] : 0;
        int s = v;
        #pragma unroll
        for (int d = 1; d < 64; d <<= 1) {
            int t = __shfl_up(s, d, 64);
            if (lane >= d) s += t;
        }
        if (lane == 63) wsum[wid] = s;
        __syncthreads();
        if (wid == 0 && lane < 16) {
            int w = wsum[lane];
            #pragma unroll
            for (int d = 1; d < 16; d <<= 1) {
                int t = __shfl_up(w, d, 64);
                if (lane >= d) w += t;
            }
            wsum[lane] = w;
        }
        __syncthreads();
        const int wpre = (wid == 0) ? 0 : wsum[wid - 1];
        if (idx < NN) offs[idx] = carry + wpre + (s - v);
        carry += wsum[15];
        __syncthreads();
    }
    if (tid == 0) offs[NN] = carry;
}

// blocks [0,1954): scatter edge ids into src-CSR. blocks [1954,+2048): tprep
// (thread (jt,o) owns 4 W2R rows in regs; j-pair-interleaved f16 stores).
__global__ __launch_bounds__(256) void scatter_tprep(
    const int* __restrict__ src, const int* __restrict__ pos_s,
    const int* __restrict__ offs_s, int* __restrict__ eidx_s,
    const float* __restrict__ x, const float* __restrict__ W2R,
    ushort* __restrict__ T)
{
    const int nbs = (NE + 255) / 256;
    if ((int)blockIdx.x < nbs) {
        const int e = blockIdx.x * 256 + threadIdx.x;
        if (e < NE) eidx_s[offs_s[src[e]] + pos_s[e]] = e;
        return;
    }
    const int bid = blockIdx.x - nbs;      // 0..2047
    const int tid = threadIdx.x;
    const int jt = tid >> 4, o = tid & 15;
    // element (j,o) lives at ushort offset (j>>1)*32 + o*2 + (j&1); for
    // j = jt+16k that is off0 + 256k with off0 below.
    const int off0 = (jt >> 1) * 32 + o * 2 + (jt & 1);

    float w0[16], w1[16], w2[16], w3[16];
    {
        const float4* p0 = reinterpret_cast<const float4*>(W2R + (jt     ) * 256 + o * 16);
        const float4* p1 = reinterpret_cast<const float4*>(W2R + (jt + 16) * 256 + o * 16);
        const float4* p2 = reinterpret_cast<const float4*>(W2R + (jt + 32) * 256 + o * 16);
        const float4* p3 = reinterpret_cast<const float4*>(W2R + (jt + 48) * 256 + o * 16);
        #pragma unroll
        for (int q = 0; q < 4; ++q) {
            float4 a = p0[q]; w0[4*q]=a.x; w0[4*q+1]=a.y; w0[4*q+2]=a.z; w0[4*q+3]=a.w;
            float4 b = p1[q]; w1[4*q]=b.x; w1[4*q+1]=b.y; w1[4*q+2]=b.z; w1[4*q+3]=b.w;
            float4 c = p2[q]; w2[4*q]=c.x; w2[4*q+1]=c.y; w2[4*q+2]=c.z; w2[4*q+3]=c.w;
            float4 d = p3[q]; w3[4*q]=d.x; w3[4*q+1]=d.y; w3[4*q+2]=d.z; w3[4*q+3]=d.w;
        }
    }
    float wb[16];
    if (jt == 0) {
        const float4* pb = reinterpret_cast<const float4*>(W2R + 64 * 256 + o * 16);
        #pragma unroll
        for (int q = 0; q < 4; ++q) {
            float4 a = pb[q]; wb[4*q]=a.x; wb[4*q+1]=a.y; wb[4*q+2]=a.z; wb[4*q+3]=a.w;
        }
    }

    for (int n = bid; n < NN; n += 2048) {
        float xr[16];
        {
            const float4* p = reinterpret_cast<const float4*>(x) + (size_t)n * 4;
            float4 a = p[0], b = p[1], c = p[2], d = p[3];
            xr[0]=a.x; xr[1]=a.y; xr[2]=a.z;  xr[3]=a.w;
            xr[4]=b.x; xr[5]=b.y; xr[6]=b.z;  xr[7]=b.w;
            xr[8]=c.x; xr[9]=c.y; xr[10]=c.z; xr[11]=c.w;
            xr[12]=d.x; xr[13]=d.y; xr[14]=d.z; xr[15]=d.w;
        }
        ushort* tw = T + (size_t)n * TROW;

        float s0 = xr[0]*w0[0], s1 = xr[0]*w1[0], s2 = xr[0]*w2[0], s3 = xr[0]*w3[0];
        #pragma unroll
        for (int i = 1; i < 16; ++i) {
            s0 = fmaf(xr[i], w0[i], s0);
            s1 = fmaf(xr[i], w1[i], s1);
            s2 = fmaf(xr[i], w2[i], s2);
            s3 = fmaf(xr[i], w3[i], s3);
        }
        tw[off0]       = f2h(s0);
        tw[off0 + 256] = f2h(s1);
        tw[off0 + 512] = f2h(s2);
        tw[off0 + 768] = f2h(s3);
        if (jt == 0) {
            float sb = xr[0]*wb[0];
            #pragma unroll
            for (int i = 1; i < 16; ++i) sb = fmaf(xr[i], wb[i], sb);
            tw[1024 + o] = f2h(sb);
        }
    }
}

// edge_msg6: 1 edge/thread; f16 j-pair T rows consumed via v_dot2_f32_f16.
// No atomics; direct dst-slot write. (r13-r15: invariant to further tweaks.)
__global__ __launch_bounds__(256) void edge_msg6(
    const int* __restrict__ eidx_s, const int* __restrict__ src,
    const int* __restrict__ dst, const float* __restrict__ ef,
    const float* __restrict__ W1T, const float* __restrict__ b1,
    const ushort* __restrict__ T, const int* __restrict__ offs_d,
    const int* __restrict__ pos_d, float* __restrict__ msgbuf)
{
    const int k = blockIdx.x * blockDim.x + threadIdx.x;
    if (k >= NE) return;
    const int e = eidx_s[k];
    const int s = src[e];

    float ea[16];
    {
        const float4* p = reinterpret_cast<const float4*>(ef) + (size_t)e * 4;
        float4 a = p[0], b = p[1], c = p[2], d = p[3];
        ea[0]=a.x; ea[1]=a.y; ea[2]=a.z;  ea[3]=a.w;
        ea[4]=b.x; ea[5]=b.y; ea[6]=b.z;  ea[7]=b.w;
        ea[8]=c.x; ea[9]=c.y; ea[10]=c.z; ea[11]=c.w;
        ea[12]=d.x; ea[13]=d.y; ea[14]=d.z; ea[15]=d.w;
    }

    const ushort* tr = T + (size_t)s * TROW;

    float m0[16];
    {   // b2 row (f16 @ offset 1024): one-time unpack
        uint4 a = *reinterpret_cast<const uint4*>(tr + 1024);
        uint4 b = *reinterpret_cast<const uint4*>(tr + 1032);
        m0[0]=h2lo(a.x);  m0[1]=h2hi(a.x);  m0[2]=h2lo(a.y);  m0[3]=h2hi(a.y);
        m0[4]=h2lo(a.z);  m0[5]=h2hi(a.z);  m0[6]=h2lo(a.w);  m0[7]=h2hi(a.w);
        m0[8]=h2lo(b.x);  m0[9]=h2hi(b.x);  m0[10]=h2lo(b.y); m0[11]=h2hi(b.y);
        m0[12]=h2lo(b.z); m0[13]=h2hi(b.z); m0[14]=h2lo(b.w); m0[15]=h2hi(b.w);
    }

    for (int jp = 0; jp < 32; ++jp) {
        const float* __restrict__ wr = W1T + jp * 32;   // rows j0=2jp, j1=2jp+1
        float h0a = b1[2 * jp], h0b = b1[2 * jp + 1];
        #pragma unroll
        for (int i = 0; i < 16; ++i) {
            h0a = fmaf(ea[i], wr[i], h0a);
            h0b = fmaf(ea[i], wr[16 + i], h0b);
        }
        h0a = fmaxf(h0a, 0.f); h0b = fmaxf(h0b, 0.f);
        const h2 hp0 = __builtin_amdgcn_cvt_pkrtz(h0a, h0b);

        const uint4 a0 = *reinterpret_cast<const uint4*>(tr + jp * 32);
        const uint4 b0 = *reinterpret_cast<const uint4*>(tr + jp * 32 + 8);
        const uint4 c0 = *reinterpret_cast<const uint4*>(tr + jp * 32 + 16);
        const uint4 d0 = *reinterpret_cast<const uint4*>(tr + jp * 32 + 24);

        m0[0]  = __builtin_amdgcn_fdot2(hp0, u2h2(a0.x), m0[0],  false);
        m0[1]  = __builtin_amdgcn_fdot2(hp0, u2h2(a0.y), m0[1],  false);
        m0[2]  = __builtin_amdgcn_fdot2(hp0, u2h2(a0.z), m0[2],  false);
        m0[3]  = __builtin_amdgcn_fdot2(hp0, u2h2(a0.w), m0[3],  false);
        m0[4]  = __builtin_amdgcn_fdot2(hp0, u2h2(b0.x), m0[4],  false);
        m0[5]  = __builtin_amdgcn_fdot2(hp0, u2h2(b0.y), m0[5],  false);
        m0[6]  = __builtin_amdgcn_fdot2(hp0, u2h2(b0.z), m0[6],  false);
        m0[7]  = __builtin_amdgcn_fdot2(hp0, u2h2(b0.w), m0[7],  false);
        m0[8]  = __builtin_amdgcn_fdot2(hp0, u2h2(c0.x), m0[8],  false);
        m0[9]  = __builtin_amdgcn_fdot2(hp0, u2h2(c0.y), m0[9],  false);
        m0[10] = __builtin_amdgcn_fdot2(hp0, u2h2(c0.z), m0[10], false);
        m0[11] = __builtin_amdgcn_fdot2(hp0, u2h2(c0.w), m0[11], false);
        m0[12] = __builtin_amdgcn_fdot2(hp0, u2h2(d0.x), m0[12], false);
        m0[13] = __builtin_amdgcn_fdot2(hp0, u2h2(d0.y), m0[13], false);
        m0[14] = __builtin_amdgcn_fdot2(hp0, u2h2(d0.z), m0[14], false);
        m0[15] = __builtin_amdgcn_fdot2(hp0, u2h2(d0.w), m0[15], false);
    }

    const int d = dst[e];
    const int slot = offs_d[d] + pos_d[e];
    float4* mr = reinterpret_cast<float4*>(msgbuf + (size_t)slot * 16);
    mr[0] = make_float4(m0[0], m0[1], m0[2], m0[3]);
    mr[1] = make_float4(m0[4], m0[5], m0[6], m0[7]);
    mr[2] = make_float4(m0[8], m0[9], m0[10], m0[11]);
    mr[3] = make_float4(m0[12], m0[13], m0[14], m0[15]);
}

// gather_mean3: thread = (node, o-quad); float4 reads/writes, 4 outputs/thread
__global__ __launch_bounds__(256) void gather_mean3(
    const float* __restrict__ msgbuf, const int* __restrict__ offs_d,
    const float* __restrict__ x, const float* __restrict__ bias,
    float* __restrict__ out)
{
    const int t = blockIdx.x * blockDim.x + threadIdx.x;
    if (t >= NN * 4) return;
    const int n = t >> 2;
    const int oq = t & 3;
    const int beg = offs_d[n], end = offs_d[n + 1];
    float4 s = make_float4(0.f, 0.f, 0.f, 0.f);
    for (int k = beg; k < end; ++k) {
        const float4 v = *reinterpret_cast<const float4*>(msgbuf + (size_t)k * 16 + oq * 4);
        s.x += v.x; s.y += v.y; s.z += v.z; s.w += v.w;
    }
    const int d = end - beg;
    float4 r;
    if (d > 0) {
        const float inv = 1.f / (float)d;
        r = make_float4(s.x * inv, s.y * inv, s.z * inv, s.w * inv);
    } else {
        r = *reinterpret_cast<const float4*>(x + (size_t)n * 16 + oq * 4);
    }
    const float4 bv = *reinterpret_cast<const float4*>(bias + oq * 4);
    r.x += bv.x; r.y += bv.y; r.z += bv.z; r.w += bv.w;
    *reinterpret_cast<float4*>(out + (size_t)n * 16 + oq * 4) = r;
}

// ===========================================================================
// FALLBACK (round-2 proven path, ~36.4 MB ws)
// ===========================================================================
__global__ __launch_bounds__(1024) void dgc_scan(
    const int* __restrict__ deg, int* __restrict__ offs, int n)
{
    __shared__ int wsum[16];
    const int tid = threadIdx.x;
    const int lane = tid & 63;
    const int wid = tid >> 6;
    int carry = 0;
    for (int base = 0; base < n; base += 1024) {
        const int idx = base + tid;
        const int v = (idx < n) ? deg[idx] : 0;
        int s = v;
        #pragma unroll
        for (int d = 1; d < 64; d <<= 1) {
            int t = __shfl_up(s, d, 64);
            if (lane >= d) s += t;
        }
        if (lane == 63) wsum[wid] = s;
        __syncthreads();
        if (wid == 0 && lane < 16) {
            int w = wsum[lane];
            #pragma unroll
            for (int d = 1; d < 16; d <<= 1) {
                int t = __shfl_up(w, d, 64);
                if (lane >= d) w += t;
            }
            wsum[lane] = w;
        }
        __syncthreads();
        const int wpre = (wid == 0) ? 0 : wsum[wid - 1];
        if (idx < n) offs[idx] = carry + wpre + (s - v);
        carry += wsum[15];
        __syncthreads();
    }
    if (tid == 0) offs[n] = carry;
}

__global__ __launch_bounds__(256) void dgc_edge_csr(
    const float* __restrict__ x, const float* __restrict__ ef,
    const int* __restrict__ src, const int* __restrict__ dst,
    const float* __restrict__ W1, const float* __restrict__ b1,
    const float* __restrict__ W2, const float* __restrict__ b2,
    float* __restrict__ msg, int* __restrict__ pos, int* __restrict__ deg)
{
    const int e = blockIdx.x * blockDim.x + threadIdx.x;
    if (e >= NE) return;
    float efv[16];
    {
        const float4* p = reinterpret_cast<const float4*>(ef) + (size_t)e * 4;
        float4 a = p[0], b = p[1], c = p[2], d = p[3];
        efv[0]=a.x; efv[1]=a.y; efv[2]=a.z;  efv[3]=a.w;
        efv[4]=b.x; efv[5]=b.y; efv[6]=b.z;  efv[7]=b.w;
        efv[8]=c.x; efv[9]=c.y; efv[10]=c.z; efv[11]=c.w;
        efv[12]=d.x; efv[13]=d.y; efv[14]=d.z; efv[15]=d.w;
    }
    const int s = src[e];
    float xs[16];
    {
        const float4* p = reinterpret_cast<const float4*>(x) + (size_t)s * 4;
        float4 a = p[0], b = p[1], c = p[2], d = p[3];
        xs[0]=a.x; xs[1]=a.y; xs[2]=a.z;  xs[3]=a.w;
        xs[4]=b.x; xs[5]=b.y; xs[6]=b.z;  xs[7]=b.w;
        xs[8]=c.x; xs[9]=c.y; xs[10]=c.z; xs[11]=c.w;
        xs[12]=d.x; xs[13]=d.y; xs[14]=d.z; xs[15]=d.w;
    }
    float m[16];
    #pragma unroll
    for (int o = 0; o < 16; ++o) m[o] = 0.f;
    #pragma unroll
    for (int i = 0; i < 16; ++i) {
        const float xi = xs[i];
        #pragma unroll
        for (int o = 0; o < 16; ++o) m[o] = fmaf(xi, b2[i * 16 + o], m[o]);
    }
    for (int j = 0; j < HID; ++j) {
        float hj = b1[j];
        #pragma unroll
        for (int i = 0; i < 16; ++i) hj = fmaf(efv[i], W1[i * HID + j], hj);
        hj = fmaxf(hj, 0.f);
        const float* __restrict__ w2r = W2 + (size_t)j * 256;
        float t[16];
        #pragma unroll
        for (int o = 0; o < 16; ++o) t[o] = 0.f;
        #pragma unroll
        for (int i = 0; i < 16; ++i) {
            const float xi = xs[i];
            #pragma unroll
            for (int o = 0; o < 16; ++o) t[o] = fmaf(xi, w2r[i * 16 + o], t[o]);
        }
        #pragma unroll
        for (int o = 0; o < 16; ++o) m[o] = fmaf(hj, t[o], m[o]);
    }
    float4* mr = reinterpret_cast<float4*>(msg + (size_t)e * 16);
    mr[0] = make_float4(m[0], m[1], m[2], m[3]);
    mr[1] = make_float4(m[4], m[5], m[6], m[7]);
    mr[2] = make_float4(m[8], m[9], m[10], m[11]);
    mr[3] = make_float4(m[12], m[13], m[14], m[15]);
    pos[e] = atomicAdd(deg + dst[e], 1);
}

__global__ __launch_bounds__(256) void dgc_scatter(
    const int* __restrict__ dst, const int* __restrict__ pos,
    const int* __restrict__ offs, int* __restrict__ eidx)
{
    const int e = blockIdx.x * blockDim.x + threadIdx.x;
    if (e >= NE) return;
    eidx[offs[dst[e]] + pos[e]] = e;
}

__global__ __launch_bounds__(256) void dgc_gather(
    const float* __restrict__ msg, const int* __restrict__ offs,
    const int* __restrict__ eidx, const float* __restrict__ x,
    const float* __restrict__ bias, float* __restrict__ out)
{
    const int t = blockIdx.x * blockDim.x + threadIdx.x;
    if (t >= NN * FOUT) return;
    const int n = t >> 4;
    const int o = t & 15;
    const int beg = offs[n], end = offs[n + 1];
    float s = 0.f;
    for (int k = beg; k < end; ++k)
        s += msg[(size_t)eidx[k] * 16 + o];
    const int d = end - beg;
    const float v = (d > 0) ? (s / (float)d) : x[t];
    out[t] = v + bias[o];
}

extern "C" void kernel_launch(void* const* d_in, const int* in_sizes, int n_in,
                              void* d_out, int out_size, void* d_ws, size_t ws_size,
                              hipStream_t stream) {
    const float* x    = (const float*)d_in[0];
    const float* ef   = (const float*)d_in[1];
    const int*   src  = (const int*)d_in[2];
    const int*   dst  = (const int*)d_in[3];
    const float* W1   = (const float*)d_in[4];
    const float* b1   = (const float*)d_in[5];
    const float* W2   = (const float*)d_in[6];
    const float* b2   = (const float*)d_in[7];
    const float* bias = (const float*)d_in[8];
    float* out = (float*)d_out;

    // main-path ws layout
    ushort* T      = (ushort*)d_ws;                       // NN*TROW f16 (104 MB)
    float*  msgbuf = (float*)(T + (size_t)NN * TROW);     // NE*16 f32   (32 MB)
    float*  W2R    = msgbuf + (size_t)NE * 16;            // 65*256
    float*  W1T    = W2R + 65 * 256;                      // 64*16
    int*    deg_s  = (int*)(W1T + 64 * 16);               // NN
    int*    deg_d  = deg_s + NN;                          // NN
    int*    offs_s = deg_d + NN;                          // NN+1
    int*    offs_d = offs_s + NN + 1;                     // NN+1
    int*    pos_s  = offs_d + NN + 1;                     // NE
    int*    pos_d  = pos_s + NE;                          // NE
    int*    eidx_s = pos_d + NE;                          // NE
    const size_t needed =
        (size_t)NN * TROW * 2 +
        ((size_t)NE * 16 + 65 * 256 + 64 * 16) * 4 +
        ((size_t)2 * NN + 2 * (NN + 1) + (size_t)3 * NE) * 4;

    const int nbc = (NE + 255) / 256;   // 1954

    if (ws_size >= needed) {
        hipMemsetAsync(deg_s, 0, (size_t)2 * NN * sizeof(int), stream);
        count_w2r<<<nbc + 65, 256, 0, stream>>>(
            src, dst, deg_s, pos_s, deg_d, pos_d, W2, b2, W1, W2R, W1T);
        dgc_scan2<<<2, 1024, 0, stream>>>(deg_s, offs_s, deg_d, offs_d);
        scatter_tprep<<<nbc + 2048, 256, 0, stream>>>(
            src, pos_s, offs_s, eidx_s, x, W2R, T);
        edge_msg6<<<nbc, 256, 0, stream>>>(
            eidx_s, src, dst, ef, W1T, b1, T, offs_d, pos_d, msgbuf);
        gather_mean3<<<(NN * 4 + 255) / 256, 256, 0, stream>>>(
            msgbuf, offs_d, x, bias, out);
    } else {
        // round-2 fallback
        float* msg  = (float*)d_ws;
        int*   deg  = (int*)(msg + (size_t)NE * 16);
        int*   offs = deg + NN;
        int*   pos  = offs + NN + 1;
        int*   eidx = pos + NE;
        hipMemsetAsync(deg, 0, (size_t)NN * sizeof(int), stream);
        dgc_edge_csr<<<(NE + 255) / 256, 256, 0, stream>>>(
            x, ef, src, dst, W1, b1, W2, b2, msg, pos, deg);
        dgc_scan<<<1, 1024, 0, stream>>>(deg, offs, NN);
        dgc_scatter<<<(NE + 255) / 256, 256, 0, stream>>>(dst, pos, offs, eidx);
        dgc_gather<<<(NN * FOUT + 255) / 256, 256, 0, stream>>>(
            msg, offs, eidx, x, bias, out);
    }
}